// Round 4
// baseline (661.787 us; speedup 1.0000x reference)
//
#include <hip/hip_runtime.h>

// ---------------------------------------------------------------------------
// Fused QKV-proj + MHA (B=4,N=1024,D=1024,H=16,DH=64), deterministic dropout.
// R4: dropout mask pre-compressed to a bitmask (268MB->8.4MB attn traffic);
//     attn adds defer-max (T13). proj/cvt/transp unchanged from R3.
// ---------------------------------------------------------------------------

typedef _Float16 f16;
typedef _Float16 f16x4 __attribute__((ext_vector_type(4)));
typedef _Float16 f16x8 __attribute__((ext_vector_type(8)));
typedef float    f32x4 __attribute__((ext_vector_type(4)));
typedef unsigned long long u64;

#define MFMA16(a, b, c) __builtin_amdgcn_mfma_f32_16x16x32_f16((a), (b), (c), 0, 0, 0)

__device__ __forceinline__ void gll16(const f16* g, f16* l) {
  __builtin_amdgcn_global_load_lds(
      (const __attribute__((address_space(1))) unsigned int*)g,
      (__attribute__((address_space(3))) unsigned int*)l, 16, 0, 0);
}

// swizzled fragment read from a [64 rows][64 f16] tile (128B rows, XOR-8 swz)
__device__ __forceinline__ f16x8 ldsfrag(const f16* tile, int row, int chunk) {
  return *(const f16x8*)&tile[row * 64 + ((chunk ^ (row & 7)) << 3)];
}

// --------------------------- convert fp32 -> hi/lo f16 ----------------------
__global__ __launch_bounds__(256) void cvt_split(const float4* __restrict__ s,
                                                 f16x4* __restrict__ hi,
                                                 f16x4* __restrict__ lo, int n4) {
  int i = blockIdx.x * 256 + threadIdx.x;
  if (i >= n4) return;
  float4 v = s[i];
  f16x4 h, l;
  h[0] = (f16)v.x; l[0] = (f16)(v.x - (float)h[0]);
  h[1] = (f16)v.y; l[1] = (f16)(v.y - (float)h[1]);
  h[2] = (f16)v.z; l[2] = (f16)(v.z - (float)h[2]);
  h[3] = (f16)v.w; l[3] = (f16)(v.w - (float)h[3]);
  hi[i] = h; lo[i] = l;
}

// --------------------------- mask -> bitmask --------------------------------
// drop_mask values are exactly 0.0 or 2.0; bit k of word [row][kw] = mask>1
// for key k = kw*64 + k. One wave does 16 ballots per row, coalesced reads.
__global__ __launch_bounds__(256) void mask_bits(const float* __restrict__ mask,
                                                 u64* __restrict__ bits) {
  const int gw = (blockIdx.x * 256 + threadIdx.x) >> 6;  // 4096 waves
  const int lane = threadIdx.x & 63;
  for (int r = gw; r < 65536; r += 4096) {  // 64 heads * 1024 rows
    const float* mrow = mask + (size_t)r * 1024;
    u64* brow = bits + (size_t)r * 16;
#pragma unroll
    for (int kw = 0; kw < 16; ++kw) {
      float v = mrow[kw * 64 + lane];
      u64 b = __ballot(v > 1.0f);
      if (lane == 0) brow[kw] = b;
    }
  }
}

// --------------------------- QKV projection GEMM ----------------------------
__global__ __launch_bounds__(256) void proj_gemm(
    const f16* __restrict__ qh, const f16* __restrict__ ql,
    const f16* __restrict__ wh, const f16* __restrict__ wl,
    const float* __restrict__ bias,
    f16* __restrict__ Qh, f16* __restrict__ Ql,
    f16* __restrict__ Kh, f16* __restrict__ Kl,
    f16* __restrict__ Vh) {
  __shared__ f16 Ah[128 * 32], Al[128 * 32], Bh[128 * 32], Bl[128 * 32];
  const int tid = threadIdx.x;
  const int bid = blockIdx.x;
  const int wg = (bid & 7) * 96 + (bid >> 3);  // XCD-chunked, 768%8==0
  const int m0 = (wg / 24) * 128, n0 = (wg % 24) * 128;
  const bool isv = (n0 >= 2048);
  const int wid = tid >> 6, lane = tid & 63;
  const int wm = (wid >> 1) * 64, wn = (wid & 1) * 64;
  const int r16 = lane & 15, g = lane >> 4;

  f32x4 zero4 = {0.f, 0.f, 0.f, 0.f};
  f32x4 acc[4][4];
#pragma unroll
  for (int i = 0; i < 4; ++i)
#pragma unroll
    for (int j = 0; j < 4; ++j) acc[i][j] = zero4;

  for (int s = 0; s < 32; ++s) {
    const int kk = s << 5;
    const f16* Abh = qh + (size_t)m0 * 1024 + kk;
    const f16* Abl = ql + (size_t)m0 * 1024 + kk;
    const f16* Bbh = wh + (size_t)n0 * 1024 + kk;
    const f16* Bbl = wl + (size_t)n0 * 1024 + kk;
#pragma unroll
    for (int it = 0; it < 2; ++it) {
      const int c = tid + it * 256;
      const int go = (c >> 2) * 1024 + (c & 3) * 8;
      gll16(Abh + go, &Ah[c * 8]);
      gll16(Bbh + go, &Bh[c * 8]);
      if (!isv) {
        gll16(Abl + go, &Al[c * 8]);
        gll16(Bbl + go, &Bl[c * 8]);
      }
    }
    __syncthreads();
    f16x8 a[4], al_[4];
#pragma unroll
    for (int i = 0; i < 4; ++i) {
      a[i] = *(const f16x8*)&Ah[(wm + i * 16 + r16) * 32 + g * 8];
      if (!isv) al_[i] = *(const f16x8*)&Al[(wm + i * 16 + r16) * 32 + g * 8];
    }
#pragma unroll
    for (int j = 0; j < 4; ++j) {
      const f16x8 b = *(const f16x8*)&Bh[(wn + j * 16 + r16) * 32 + g * 8];
      if (!isv) {
        const f16x8 bl = *(const f16x8*)&Bl[(wn + j * 16 + r16) * 32 + g * 8];
#pragma unroll
        for (int i = 0; i < 4; ++i) {
          acc[i][j] = MFMA16(a[i], b, acc[i][j]);
          acc[i][j] = MFMA16(al_[i], b, acc[i][j]);
          acc[i][j] = MFMA16(a[i], bl, acc[i][j]);
        }
      } else {
#pragma unroll
        for (int i = 0; i < 4; ++i) acc[i][j] = MFMA16(a[i], b, acc[i][j]);
      }
    }
    __syncthreads();
  }

#pragma unroll
  for (int j = 0; j < 4; ++j) {
    const int col = n0 + wn + j * 16 + r16;
    const float bv = bias[col];
#pragma unroll
    for (int i = 0; i < 4; ++i) {
#pragma unroll
      for (int rr = 0; rr < 4; ++rr) {
        const int m = m0 + wm + i * 16 + g * 4 + rr;
        const float c = acc[i][j][rr] + bv;
        const int bi = m >> 10, n = m & 1023;
        if (col < 1024) {
          const int z = bi * 16 + (col >> 6), dh = col & 63;
          const size_t idx = ((size_t)z * 1024 + n) * 64 + dh;
          f16 h = (f16)c;
          Qh[idx] = h; Ql[idx] = (f16)(c - (float)h);
        } else if (col < 2048) {
          const int c2 = col - 1024;
          const int z = bi * 16 + (c2 >> 6), dh = c2 & 63;
          const size_t idx = ((size_t)z * 1024 + n) * 64 + dh;
          f16 h = (f16)c;
          Kh[idx] = h; Kl[idx] = (f16)(c - (float)h);
        } else {
          const int c2 = col - 2048;
          const int z = bi * 16 + (c2 >> 6), dh = c2 & 63;
          Vh[((size_t)z * 1024 + n) * 64 + dh] = (f16)c;
        }
      }
    }
  }
}

// --------------------------- V transpose ------------------------------------
__global__ __launch_bounds__(256) void transp_v(const f16* __restrict__ Vh,
                                                f16* __restrict__ Vt) {
  __shared__ f16 t[64][80];
  const int z = blockIdx.y, nt = blockIdx.x;
  const int tid = threadIdx.x;
#pragma unroll
  for (int it = 0; it < 2; ++it) {
    int c = tid + it * 256;
    int row = c >> 3, cc = c & 7;
    *(f16x8*)&t[row][cc * 8] =
        *(const f16x8*)&Vh[(((size_t)z << 10) + nt * 64 + row) * 64 + cc * 8];
  }
  __syncthreads();
#pragma unroll
  for (int it = 0; it < 2; ++it) {
    int c = tid + it * 256;
    int dh = c >> 3, ncc = c & 7;
    f16x8 o;
#pragma unroll
    for (int j = 0; j < 8; ++j) o[j] = t[ncc * 8 + j][dh];
    *(f16x8*)&Vt[((size_t)z * 64 + dh) * 1024 + nt * 64 + ncc * 8] = o;
  }
}

// --------------------------- fused attention --------------------------------
// 8 waves (512 thr); block = head z x 128 q-rows; 16 k-tiles of 64.
// 2-phase pipeline (STAGE(next) before compute(cur), 1 barrier/tile).
// Dropout via bitmask (8B/row/tile); defer-max with THR=8.
__global__ __launch_bounds__(512) void attn(
    const f16* __restrict__ Qh_, const f16* __restrict__ Ql_,
    const f16* __restrict__ Kh_, const f16* __restrict__ Kl_,
    const f16* __restrict__ Vt_, const u64* __restrict__ bits,
    float* __restrict__ out) {
  __shared__ f16 Khs[2][4096], Kls[2][4096], Vts[2][4096];  // 48 KB dbuf
  __shared__ f16 Ps[8][1024];                               // 16 KB P tiles

  const int bid = blockIdx.x;
  const int wg = (bid & 7) * 64 + (bid >> 3);  // XCD-chunked, 512%8==0
  const int qt = wg & 7, z = wg >> 3;
  const int q0 = qt * 128;
  const int tid = threadIdx.x, w = tid >> 6, lane = tid & 63;
  const int r16 = lane & 15, g = lane >> 4;

  const size_t zrow = (size_t)z << 10;
  const f16* qrh = Qh_ + (zrow + q0 + w * 16 + r16) * 64;
  const f16* qrl = Ql_ + (zrow + q0 + w * 16 + r16) * 64;
  f16x8 qa[2], qla[2];
#pragma unroll
  for (int ks = 0; ks < 2; ++ks) {
    qa[ks] = *(const f16x8*)&qrh[ks * 32 + g * 8];
    qla[ks] = *(const f16x8*)&qrl[ks * 32 + g * 8];
  }

  const f16* KzhB = Kh_ + zrow * 64;
  const f16* KzlB = Kl_ + zrow * 64;
  const f16* VzB = Vt_ + (size_t)z * 64 * 1024;
  const int sc = tid, srow = sc >> 3, ssc = ((sc & 7) ^ (srow & 7)) << 3;

#define STAGE(buf, k0_)                                                   \
  do {                                                                    \
    gll16(KzhB + (size_t)((k0_) + srow) * 64 + ssc, &Khs[buf][sc * 8]);   \
    gll16(KzlB + (size_t)((k0_) + srow) * 64 + ssc, &Kls[buf][sc * 8]);   \
    gll16(VzB + (size_t)srow * 1024 + (k0_) + ssc, &Vts[buf][sc * 8]);    \
  } while (0)

  STAGE(0, 0);

  float mrow[4] = {-1e30f, -1e30f, -1e30f, -1e30f};
  float lrow[4] = {0.f, 0.f, 0.f, 0.f};
  f32x4 zero4 = {0.f, 0.f, 0.f, 0.f};
  f32x4 acc[4];
#pragma unroll
  for (int df = 0; df < 4; ++df) acc[df] = zero4;

  // bitmask row pointers for this thread's 4 q-rows
  const int qrow_m = q0 + w * 16 + g * 4;
  const u64* brow = bits + (zrow + qrow_m) * 16;
  f16* Pw = &Ps[w][0];
  __syncthreads();

  for (int kt = 0; kt < 16; ++kt) {
    const int cur = kt & 1;
    const int k0 = kt << 6;
    if (kt < 15) STAGE(cur ^ 1, k0 + 64);  // async prefetch of next tile

    // dropout bitmask words for this tile (8B per q-row)
    u64 bm[4];
#pragma unroll
    for (int rr = 0; rr < 4; ++rr) bm[rr] = brow[rr * 16 + kt];

    // ---- S = Q K^T, 3-term hi/lo ----
    __builtin_amdgcn_s_setprio(1);
    f32x4 s[4];
#pragma unroll
    for (int cf = 0; cf < 4; ++cf) {
      const int krow = cf * 16 + r16;
      const f16x8 kh0 = ldsfrag(&Khs[cur][0], krow, g);
      const f16x8 kh1 = ldsfrag(&Khs[cur][0], krow, 4 + g);
      const f16x8 kl0 = ldsfrag(&Kls[cur][0], krow, g);
      const f16x8 kl1 = ldsfrag(&Kls[cur][0], krow, 4 + g);
      f32x4 t = zero4;
      t = MFMA16(qa[0], kh0, t);
      t = MFMA16(qla[0], kh0, t);
      t = MFMA16(qa[0], kl0, t);
      t = MFMA16(qa[1], kh1, t);
      t = MFMA16(qla[1], kh1, t);
      t = MFMA16(qa[1], kl1, t);
      s[cf] = t;
    }
    __builtin_amdgcn_s_setprio(0);

    // ---- online softmax (scores *8 per reference quirk) ----
    float s8[4][4];
#pragma unroll
    for (int cf = 0; cf < 4; ++cf)
#pragma unroll
      for (int rr = 0; rr < 4; ++rr) s8[cf][rr] = s[cf][rr] * 8.0f;

    float rm[4];
#pragma unroll
    for (int rr = 0; rr < 4; ++rr)
      rm[rr] = fmaxf(fmaxf(s8[0][rr], s8[1][rr]), fmaxf(s8[2][rr], s8[3][rr]));
#pragma unroll
    for (int mk = 1; mk < 16; mk <<= 1)
#pragma unroll
      for (int rr = 0; rr < 4; ++rr)
        rm[rr] = fmaxf(rm[rr], __shfl_xor(rm[rr], mk, 64));

    // ---- defer-max (T13): rescale only if max grew by > 8 ----
    const int nogrow = __all((rm[0] <= mrow[0] + 8.f) & (rm[1] <= mrow[1] + 8.f) &
                             (rm[2] <= mrow[2] + 8.f) & (rm[3] <= mrow[3] + 8.f));
    if (!nogrow) {
      float scal[4];
#pragma unroll
      for (int rr = 0; rr < 4; ++rr) {
        const float mnew = fmaxf(mrow[rr], rm[rr]);
        scal[rr] = __expf(mrow[rr] - mnew);
        mrow[rr] = mnew;
        lrow[rr] *= scal[rr];
      }
#pragma unroll
      for (int df = 0; df < 4; ++df)
#pragma unroll
        for (int rr = 0; rr < 4; ++rr) acc[df][rr] *= scal[rr];
    }

    float p_[4][4], rs[4] = {0.f, 0.f, 0.f, 0.f};
#pragma unroll
    for (int cf = 0; cf < 4; ++cf)
#pragma unroll
      for (int rr = 0; rr < 4; ++rr) {
        p_[cf][rr] = __expf(s8[cf][rr] - mrow[rr]);
        rs[rr] += p_[cf][rr];
      }
#pragma unroll
    for (int mk = 1; mk < 16; mk <<= 1)
#pragma unroll
      for (int rr = 0; rr < 4; ++rr) rs[rr] += __shfl_xor(rs[rr], mk, 64);
#pragma unroll
    for (int rr = 0; rr < 4; ++rr) lrow[rr] += rs[rr];

    // ---- dropout bit-select + P (f16) through wave-private swizzled LDS ----
#pragma unroll
    for (int cf = 0; cf < 4; ++cf)
#pragma unroll
      for (int rr = 0; rr < 4; ++rr) {
        const int prow = g * 4 + rr, key = cf * 16 + r16;
        const float pm =
            ((bm[rr] >> key) & 1ull) ? p_[cf][rr] + p_[cf][rr] : 0.0f;
        Pw[prow * 64 + (((key >> 3) ^ (prow & 7)) << 3) + (key & 7)] = (f16)pm;
      }
    f16x8 pf[2];
#pragma unroll
    for (int ks2 = 0; ks2 < 2; ++ks2)
      pf[ks2] = ldsfrag(Pw, r16, ks2 * 4 + g);

    // ---- PV from staged V^T tile ----
    __builtin_amdgcn_s_setprio(1);
#pragma unroll
    for (int df = 0; df < 4; ++df)
#pragma unroll
      for (int ks2 = 0; ks2 < 2; ++ks2)
        acc[df] = MFMA16(pf[ks2],
                         ldsfrag(&Vts[cur][0], df * 16 + r16, ks2 * 4 + g),
                         acc[df]);
    __builtin_amdgcn_s_setprio(0);
    __syncthreads();
  }

  // ---- epilogue ----
  const int bi = z >> 4, hh = z & 15;
#pragma unroll
  for (int df = 0; df < 4; ++df)
#pragma unroll
    for (int rr = 0; rr < 4; ++rr) {
      const int n = q0 + w * 16 + g * 4 + rr;
      out[((size_t)bi * 1024 + n) * 1024 + hh * 64 + df * 16 + r16] =
          acc[df][rr] / lrow[rr];
    }
#undef STAGE
}

// --------------------------- launcher ---------------------------------------
extern "C" void kernel_launch(void* const* d_in, const int* in_sizes, int n_in,
                              void* d_out, int out_size, void* d_ws,
                              size_t ws_size, hipStream_t stream) {
  const float* query = (const float*)d_in[0];
  const float* W = (const float*)d_in[3];
  const float* bias = (const float*)d_in[4];
  const float* mask = (const float*)d_in[5];
  float* out = (float*)d_out;

  f16* p = (f16*)d_ws;
  f16* qh = p;              p += (size_t)4096 * 1024;
  f16* ql = p;              p += (size_t)4096 * 1024;
  f16* wh = p;              p += (size_t)3072 * 1024;
  f16* wl = p;              p += (size_t)3072 * 1024;
  f16* Qh = p;              p += (size_t)64 * 1024 * 64;
  f16* Ql = p;              p += (size_t)64 * 1024 * 64;
  f16* Kh = p;              p += (size_t)64 * 1024 * 64;
  f16* Kl = p;              p += (size_t)64 * 1024 * 64;
  f16* Vh = p;              p += (size_t)64 * 1024 * 64;
  f16* Vt = p;              p += (size_t)64 * 1024 * 64;
  u64* bits = (u64*)p;      // 64*1024*16 u64 = 8.4 MB

  mask_bits<<<1024, 256, 0, stream>>>(mask, bits);
  cvt_split<<<(1048576 + 255) / 256, 256, 0, stream>>>(
      (const float4*)query, (f16x4*)qh, (f16x4*)ql, 1048576);
  cvt_split<<<(786432 + 255) / 256, 256, 0, stream>>>(
      (const float4*)W, (f16x4*)wh, (f16x4*)wl, 786432);
  proj_gemm<<<768, 256, 0, stream>>>(qh, ql, wh, wl, bias, Qh, Ql, Kh, Kl, Vh);
  transp_v<<<dim3(16, 64), 256, 0, stream>>>(Vh, Vt);
  attn<<<512, 512, 0, stream>>>(Qh, Ql, Kh, Kl, Vt, bits, out);
}

// Round 5
// 573.940 us; speedup vs baseline: 1.1531x; 1.1531x over previous
//
#include <hip/hip_runtime.h>

// ---------------------------------------------------------------------------
// Fused QKV-proj + MHA (B=4,N=1024,D=1024,H=16,DH=64), deterministic dropout.
// R5: mask_bits rewritten (no ballot, 16-bit pack per thread, ~20 VGPR);
//     proj_gemm double-buffered with prefetch-before-compute (attn pattern).
//     attn unchanged from R4 (bitmask + defer-max, 2-phase pipeline).
// ---------------------------------------------------------------------------

typedef _Float16 f16;
typedef _Float16 f16x4 __attribute__((ext_vector_type(4)));
typedef _Float16 f16x8 __attribute__((ext_vector_type(8)));
typedef float    f32x4 __attribute__((ext_vector_type(4)));
typedef unsigned long long u64;
typedef unsigned short u16;

#define MFMA16(a, b, c) __builtin_amdgcn_mfma_f32_16x16x32_f16((a), (b), (c), 0, 0, 0)

__device__ __forceinline__ void gll16(const f16* g, f16* l) {
  __builtin_amdgcn_global_load_lds(
      (const __attribute__((address_space(1))) unsigned int*)g,
      (__attribute__((address_space(3))) unsigned int*)l, 16, 0, 0);
}

// swizzled fragment read from a [64 rows][64 f16] tile (128B rows, XOR-8 swz)
__device__ __forceinline__ f16x8 ldsfrag(const f16* tile, int row, int chunk) {
  return *(const f16x8*)&tile[row * 64 + ((chunk ^ (row & 7)) << 3)];
}

// --------------------------- convert fp32 -> hi/lo f16 ----------------------
__global__ __launch_bounds__(256) void cvt_split(const float4* __restrict__ s,
                                                 f16x4* __restrict__ hi,
                                                 f16x4* __restrict__ lo, int n4) {
  int i = blockIdx.x * 256 + threadIdx.x;
  if (i >= n4) return;
  float4 v = s[i];
  f16x4 h, l;
  h[0] = (f16)v.x; l[0] = (f16)(v.x - (float)h[0]);
  h[1] = (f16)v.y; l[1] = (f16)(v.y - (float)h[1]);
  h[2] = (f16)v.z; l[2] = (f16)(v.z - (float)h[2]);
  h[3] = (f16)v.w; l[3] = (f16)(v.w - (float)h[3]);
  hi[i] = h; lo[i] = l;
}

// --------------------------- mask -> bitmask --------------------------------
// Each thread: 16 consecutive floats (4x float4), pack 16 bits, 1 ushort
// store. No cross-lane ops, no dependent chains -> load-BW bound.
// bits16[t] covers keys [16t, 16t+16) -> identical u64 layout to R4.
__global__ __launch_bounds__(256) void mask_bits(const float4* __restrict__ mask,
                                                 u16* __restrict__ bits16) {
  const size_t t = (size_t)blockIdx.x * 256 + threadIdx.x;  // 4,194,304 threads
  const float4 v0 = mask[t * 4 + 0];
  const float4 v1 = mask[t * 4 + 1];
  const float4 v2 = mask[t * 4 + 2];
  const float4 v3 = mask[t * 4 + 3];
  unsigned m = 0;
  m |= (v0.x > 1.f) ? 0x0001u : 0u;  m |= (v0.y > 1.f) ? 0x0002u : 0u;
  m |= (v0.z > 1.f) ? 0x0004u : 0u;  m |= (v0.w > 1.f) ? 0x0008u : 0u;
  m |= (v1.x > 1.f) ? 0x0010u : 0u;  m |= (v1.y > 1.f) ? 0x0020u : 0u;
  m |= (v1.z > 1.f) ? 0x0040u : 0u;  m |= (v1.w > 1.f) ? 0x0080u : 0u;
  m |= (v2.x > 1.f) ? 0x0100u : 0u;  m |= (v2.y > 1.f) ? 0x0200u : 0u;
  m |= (v2.z > 1.f) ? 0x0400u : 0u;  m |= (v2.w > 1.f) ? 0x0800u : 0u;
  m |= (v3.x > 1.f) ? 0x1000u : 0u;  m |= (v3.y > 1.f) ? 0x2000u : 0u;
  m |= (v3.z > 1.f) ? 0x4000u : 0u;  m |= (v3.w > 1.f) ? 0x8000u : 0u;
  bits16[t] = (u16)m;
}

// --------------------------- QKV projection GEMM ----------------------------
// C[4096][3072] = query @ W^T + b. 128x128 tile, BK=32, 4 waves.
// R5: double-buffered LDS (64KB), STAGE(next) before compute(cur).
__global__ __launch_bounds__(256) void proj_gemm(
    const f16* __restrict__ qh, const f16* __restrict__ ql,
    const f16* __restrict__ wh, const f16* __restrict__ wl,
    const float* __restrict__ bias,
    f16* __restrict__ Qh, f16* __restrict__ Ql,
    f16* __restrict__ Kh, f16* __restrict__ Kl,
    f16* __restrict__ Vh) {
  __shared__ f16 Ah[2][128 * 32], Al[2][128 * 32];
  __shared__ f16 Bh[2][128 * 32], Bl[2][128 * 32];  // 64 KB total
  const int tid = threadIdx.x;
  const int bid = blockIdx.x;
  const int wg = (bid & 7) * 96 + (bid >> 3);  // XCD-chunked, 768%8==0
  const int m0 = (wg / 24) * 128, n0 = (wg % 24) * 128;
  const bool isv = (n0 >= 2048);
  const int wid = tid >> 6, lane = tid & 63;
  const int wm = (wid >> 1) * 64, wn = (wid & 1) * 64;
  const int r16 = lane & 15, g = lane >> 4;

  // per-thread staging chunk geometry (2 chunks of 16B per array per step)
  const int c0 = tid, c1 = tid + 256;
  const int go0 = (c0 >> 2) * 1024 + (c0 & 3) * 8;
  const int go1 = (c1 >> 2) * 1024 + (c1 & 3) * 8;
  const f16* Aqh = qh + (size_t)m0 * 1024;
  const f16* Aql = ql + (size_t)m0 * 1024;
  const f16* Bwh = wh + (size_t)n0 * 1024;
  const f16* Bwl = wl + (size_t)n0 * 1024;

#define PSTAGE(buf, kk_)                                  \
  do {                                                    \
    gll16(Aqh + (kk_) + go0, &Ah[buf][c0 * 8]);           \
    gll16(Aqh + (kk_) + go1, &Ah[buf][c1 * 8]);           \
    gll16(Bwh + (kk_) + go0, &Bh[buf][c0 * 8]);           \
    gll16(Bwh + (kk_) + go1, &Bh[buf][c1 * 8]);           \
    if (!isv) {                                           \
      gll16(Aql + (kk_) + go0, &Al[buf][c0 * 8]);         \
      gll16(Aql + (kk_) + go1, &Al[buf][c1 * 8]);         \
      gll16(Bwl + (kk_) + go0, &Bl[buf][c0 * 8]);         \
      gll16(Bwl + (kk_) + go1, &Bl[buf][c1 * 8]);         \
    }                                                     \
  } while (0)

  f32x4 zero4 = {0.f, 0.f, 0.f, 0.f};
  f32x4 acc[4][4];
#pragma unroll
  for (int i = 0; i < 4; ++i)
#pragma unroll
    for (int j = 0; j < 4; ++j) acc[i][j] = zero4;

  PSTAGE(0, 0);
  __syncthreads();

  for (int s = 0; s < 32; ++s) {
    const int cur = s & 1;
    if (s < 31) PSTAGE(cur ^ 1, (s + 1) << 5);  // async prefetch of next step

    f16x8 a[4], al_[4];
#pragma unroll
    for (int i = 0; i < 4; ++i) {
      a[i] = *(const f16x8*)&Ah[cur][(wm + i * 16 + r16) * 32 + g * 8];
      if (!isv)
        al_[i] = *(const f16x8*)&Al[cur][(wm + i * 16 + r16) * 32 + g * 8];
    }
#pragma unroll
    for (int j = 0; j < 4; ++j) {
      const f16x8 b = *(const f16x8*)&Bh[cur][(wn + j * 16 + r16) * 32 + g * 8];
      if (!isv) {
        const f16x8 bl =
            *(const f16x8*)&Bl[cur][(wn + j * 16 + r16) * 32 + g * 8];
#pragma unroll
        for (int i = 0; i < 4; ++i) {
          acc[i][j] = MFMA16(a[i], b, acc[i][j]);
          acc[i][j] = MFMA16(al_[i], b, acc[i][j]);
          acc[i][j] = MFMA16(a[i], bl, acc[i][j]);
        }
      } else {
#pragma unroll
        for (int i = 0; i < 4; ++i) acc[i][j] = MFMA16(a[i], b, acc[i][j]);
      }
    }
    __syncthreads();  // prefetch landed + all reads of cur done
  }
#undef PSTAGE

  // epilogue: C layout col=lane&15, row=(lane>>4)*4+reg
#pragma unroll
  for (int j = 0; j < 4; ++j) {
    const int col = n0 + wn + j * 16 + r16;
    const float bv = bias[col];
#pragma unroll
    for (int i = 0; i < 4; ++i) {
#pragma unroll
      for (int rr = 0; rr < 4; ++rr) {
        const int m = m0 + wm + i * 16 + g * 4 + rr;
        const float c = acc[i][j][rr] + bv;
        const int bi = m >> 10, n = m & 1023;
        if (col < 1024) {
          const int z = bi * 16 + (col >> 6), dh = col & 63;
          const size_t idx = ((size_t)z * 1024 + n) * 64 + dh;
          f16 h = (f16)c;
          Qh[idx] = h; Ql[idx] = (f16)(c - (float)h);
        } else if (col < 2048) {
          const int c2 = col - 1024;
          const int z = bi * 16 + (c2 >> 6), dh = c2 & 63;
          const size_t idx = ((size_t)z * 1024 + n) * 64 + dh;
          f16 h = (f16)c;
          Kh[idx] = h; Kl[idx] = (f16)(c - (float)h);
        } else {
          const int c2 = col - 2048;
          const int z = bi * 16 + (c2 >> 6), dh = c2 & 63;
          Vh[((size_t)z * 1024 + n) * 64 + dh] = (f16)c;
        }
      }
    }
  }
}

// --------------------------- V transpose ------------------------------------
__global__ __launch_bounds__(256) void transp_v(const f16* __restrict__ Vh,
                                                f16* __restrict__ Vt) {
  __shared__ f16 t[64][80];
  const int z = blockIdx.y, nt = blockIdx.x;
  const int tid = threadIdx.x;
#pragma unroll
  for (int it = 0; it < 2; ++it) {
    int c = tid + it * 256;
    int row = c >> 3, cc = c & 7;
    *(f16x8*)&t[row][cc * 8] =
        *(const f16x8*)&Vh[(((size_t)z << 10) + nt * 64 + row) * 64 + cc * 8];
  }
  __syncthreads();
#pragma unroll
  for (int it = 0; it < 2; ++it) {
    int c = tid + it * 256;
    int dh = c >> 3, ncc = c & 7;
    f16x8 o;
#pragma unroll
    for (int j = 0; j < 8; ++j) o[j] = t[ncc * 8 + j][dh];
    *(f16x8*)&Vt[((size_t)z * 64 + dh) * 1024 + nt * 64 + ncc * 8] = o;
  }
}

// --------------------------- fused attention --------------------------------
// 8 waves (512 thr); block = head z x 128 q-rows; 16 k-tiles of 64.
// 2-phase pipeline (STAGE(next) before compute(cur), 1 barrier/tile).
// Dropout via bitmask (8B/row/tile); defer-max with THR=8.
__global__ __launch_bounds__(512) void attn(
    const f16* __restrict__ Qh_, const f16* __restrict__ Ql_,
    const f16* __restrict__ Kh_, const f16* __restrict__ Kl_,
    const f16* __restrict__ Vt_, const u64* __restrict__ bits,
    float* __restrict__ out) {
  __shared__ f16 Khs[2][4096], Kls[2][4096], Vts[2][4096];  // 48 KB dbuf
  __shared__ f16 Ps[8][1024];                               // 16 KB P tiles

  const int bid = blockIdx.x;
  const int wg = (bid & 7) * 64 + (bid >> 3);  // XCD-chunked, 512%8==0
  const int qt = wg & 7, z = wg >> 3;
  const int q0 = qt * 128;
  const int tid = threadIdx.x, w = tid >> 6, lane = tid & 63;
  const int r16 = lane & 15, g = lane >> 4;

  const size_t zrow = (size_t)z << 10;
  const f16* qrh = Qh_ + (zrow + q0 + w * 16 + r16) * 64;
  const f16* qrl = Ql_ + (zrow + q0 + w * 16 + r16) * 64;
  f16x8 qa[2], qla[2];
#pragma unroll
  for (int ks = 0; ks < 2; ++ks) {
    qa[ks] = *(const f16x8*)&qrh[ks * 32 + g * 8];
    qla[ks] = *(const f16x8*)&qrl[ks * 32 + g * 8];
  }

  const f16* KzhB = Kh_ + zrow * 64;
  const f16* KzlB = Kl_ + zrow * 64;
  const f16* VzB = Vt_ + (size_t)z * 64 * 1024;
  const int sc = tid, srow = sc >> 3, ssc = ((sc & 7) ^ (srow & 7)) << 3;

#define STAGE(buf, k0_)                                                   \
  do {                                                                    \
    gll16(KzhB + (size_t)((k0_) + srow) * 64 + ssc, &Khs[buf][sc * 8]);   \
    gll16(KzlB + (size_t)((k0_) + srow) * 64 + ssc, &Kls[buf][sc * 8]);   \
    gll16(VzB + (size_t)srow * 1024 + (k0_) + ssc, &Vts[buf][sc * 8]);    \
  } while (0)

  STAGE(0, 0);

  float mrow[4] = {-1e30f, -1e30f, -1e30f, -1e30f};
  float lrow[4] = {0.f, 0.f, 0.f, 0.f};
  f32x4 zero4 = {0.f, 0.f, 0.f, 0.f};
  f32x4 acc[4];
#pragma unroll
  for (int df = 0; df < 4; ++df) acc[df] = zero4;

  const int qrow_m = q0 + w * 16 + g * 4;
  const u64* brow = bits + (zrow + qrow_m) * 16;
  f16* Pw = &Ps[w][0];
  __syncthreads();

  for (int kt = 0; kt < 16; ++kt) {
    const int cur = kt & 1;
    const int k0 = kt << 6;
    if (kt < 15) STAGE(cur ^ 1, k0 + 64);  // async prefetch of next tile

    u64 bm[4];
#pragma unroll
    for (int rr = 0; rr < 4; ++rr) bm[rr] = brow[rr * 16 + kt];

    // ---- S = Q K^T, 3-term hi/lo ----
    __builtin_amdgcn_s_setprio(1);
    f32x4 s[4];
#pragma unroll
    for (int cf = 0; cf < 4; ++cf) {
      const int krow = cf * 16 + r16;
      const f16x8 kh0 = ldsfrag(&Khs[cur][0], krow, g);
      const f16x8 kh1 = ldsfrag(&Khs[cur][0], krow, 4 + g);
      const f16x8 kl0 = ldsfrag(&Kls[cur][0], krow, g);
      const f16x8 kl1 = ldsfrag(&Kls[cur][0], krow, 4 + g);
      f32x4 t = zero4;
      t = MFMA16(qa[0], kh0, t);
      t = MFMA16(qla[0], kh0, t);
      t = MFMA16(qa[0], kl0, t);
      t = MFMA16(qa[1], kh1, t);
      t = MFMA16(qla[1], kh1, t);
      t = MFMA16(qa[1], kl1, t);
      s[cf] = t;
    }
    __builtin_amdgcn_s_setprio(0);

    // ---- online softmax (scores *8 per reference quirk) ----
    float s8[4][4];
#pragma unroll
    for (int cf = 0; cf < 4; ++cf)
#pragma unroll
      for (int rr = 0; rr < 4; ++rr) s8[cf][rr] = s[cf][rr] * 8.0f;

    float rm[4];
#pragma unroll
    for (int rr = 0; rr < 4; ++rr)
      rm[rr] = fmaxf(fmaxf(s8[0][rr], s8[1][rr]), fmaxf(s8[2][rr], s8[3][rr]));
#pragma unroll
    for (int mk = 1; mk < 16; mk <<= 1)
#pragma unroll
      for (int rr = 0; rr < 4; ++rr)
        rm[rr] = fmaxf(rm[rr], __shfl_xor(rm[rr], mk, 64));

    // ---- defer-max (T13): rescale only if max grew by > 8 ----
    const int nogrow = __all((rm[0] <= mrow[0] + 8.f) & (rm[1] <= mrow[1] + 8.f) &
                             (rm[2] <= mrow[2] + 8.f) & (rm[3] <= mrow[3] + 8.f));
    if (!nogrow) {
      float scal[4];
#pragma unroll
      for (int rr = 0; rr < 4; ++rr) {
        const float mnew = fmaxf(mrow[rr], rm[rr]);
        scal[rr] = __expf(mrow[rr] - mnew);
        mrow[rr] = mnew;
        lrow[rr] *= scal[rr];
      }
#pragma unroll
      for (int df = 0; df < 4; ++df)
#pragma unroll
        for (int rr = 0; rr < 4; ++rr) acc[df][rr] *= scal[rr];
    }

    float p_[4][4], rs[4] = {0.f, 0.f, 0.f, 0.f};
#pragma unroll
    for (int cf = 0; cf < 4; ++cf)
#pragma unroll
      for (int rr = 0; rr < 4; ++rr) {
        p_[cf][rr] = __expf(s8[cf][rr] - mrow[rr]);
        rs[rr] += p_[cf][rr];
      }
#pragma unroll
    for (int mk = 1; mk < 16; mk <<= 1)
#pragma unroll
      for (int rr = 0; rr < 4; ++rr) rs[rr] += __shfl_xor(rs[rr], mk, 64);
#pragma unroll
    for (int rr = 0; rr < 4; ++rr) lrow[rr] += rs[rr];

    // ---- dropout bit-select + P (f16) through wave-private swizzled LDS ----
#pragma unroll
    for (int cf = 0; cf < 4; ++cf)
#pragma unroll
      for (int rr = 0; rr < 4; ++rr) {
        const int prow = g * 4 + rr, key = cf * 16 + r16;
        const float pm =
            ((bm[rr] >> key) & 1ull) ? p_[cf][rr] + p_[cf][rr] : 0.0f;
        Pw[prow * 64 + (((key >> 3) ^ (prow & 7)) << 3) + (key & 7)] = (f16)pm;
      }
    f16x8 pf[2];
#pragma unroll
    for (int ks2 = 0; ks2 < 2; ++ks2)
      pf[ks2] = ldsfrag(Pw, r16, ks2 * 4 + g);

    // ---- PV from staged V^T tile ----
    __builtin_amdgcn_s_setprio(1);
#pragma unroll
    for (int df = 0; df < 4; ++df)
#pragma unroll
      for (int ks2 = 0; ks2 < 2; ++ks2)
        acc[df] = MFMA16(pf[ks2],
                         ldsfrag(&Vts[cur][0], df * 16 + r16, ks2 * 4 + g),
                         acc[df]);
    __builtin_amdgcn_s_setprio(0);
    __syncthreads();
  }

  // ---- epilogue ----
  const int bi = z >> 4, hh = z & 15;
#pragma unroll
  for (int df = 0; df < 4; ++df)
#pragma unroll
    for (int rr = 0; rr < 4; ++rr) {
      const int n = q0 + w * 16 + g * 4 + rr;
      out[((size_t)bi * 1024 + n) * 1024 + hh * 64 + df * 16 + r16] =
          acc[df][rr] / lrow[rr];
    }
#undef STAGE
}

// --------------------------- launcher ---------------------------------------
extern "C" void kernel_launch(void* const* d_in, const int* in_sizes, int n_in,
                              void* d_out, int out_size, void* d_ws,
                              size_t ws_size, hipStream_t stream) {
  const float* query = (const float*)d_in[0];
  const float* W = (const float*)d_in[3];
  const float* bias = (const float*)d_in[4];
  const float* mask = (const float*)d_in[5];
  float* out = (float*)d_out;

  f16* p = (f16*)d_ws;
  f16* qh = p;              p += (size_t)4096 * 1024;
  f16* ql = p;              p += (size_t)4096 * 1024;
  f16* wh = p;              p += (size_t)3072 * 1024;
  f16* wl = p;              p += (size_t)3072 * 1024;
  f16* Qh = p;              p += (size_t)64 * 1024 * 64;
  f16* Ql = p;              p += (size_t)64 * 1024 * 64;
  f16* Kh = p;              p += (size_t)64 * 1024 * 64;
  f16* Kl = p;              p += (size_t)64 * 1024 * 64;
  f16* Vh = p;              p += (size_t)64 * 1024 * 64;
  f16* Vt = p;              p += (size_t)64 * 1024 * 64;
  u64* bits = (u64*)p;      // 64*1024*16 u64 = 8.4 MB

  mask_bits<<<16384, 256, 0, stream>>>((const float4*)mask, (u16*)bits);
  cvt_split<<<(1048576 + 255) / 256, 256, 0, stream>>>(
      (const float4*)query, (f16x4*)qh, (f16x4*)ql, 1048576);
  cvt_split<<<(786432 + 255) / 256, 256, 0, stream>>>(
      (const float4*)W, (f16x4*)wh, (f16x4*)wl, 786432);
  proj_gemm<<<768, 256, 0, stream>>>(qh, ql, wh, wl, bias, Qh, Ql, Kh, Kl, Vh);
  transp_v<<<dim3(16, 64), 256, 0, stream>>>(Vh, Vt);
  attn<<<512, 512, 0, stream>>>(Qh, Ql, Kh, Kl, Vt, bits, out);
}

// Round 8
// 568.703 us; speedup vs baseline: 1.1637x; 1.0092x over previous
//
#include <hip/hip_runtime.h>

// ---------------------------------------------------------------------------
// Fused QKV-proj + MHA (B=4,N=1024,D=1024,H=16,DH=64), deterministic dropout.
// R6 kernel, third submission (two infra-failed rounds):
//     proj single-buffer 32KB (R5 dbuf cost occupancy, m132).
//     attn with SWAPPED QK^T: S^T = mfma(K,Q) puts a full q-row in one lane
//     -> row reduce = 15 VALU + 2 shfl (was 32 shfl), P-write = 4x
//     ds_write_b64 (was 16x b16), scalar m/l state. Layout per m89 C-map.
// ---------------------------------------------------------------------------

typedef _Float16 f16;
typedef _Float16 f16x4 __attribute__((ext_vector_type(4)));
typedef _Float16 f16x8 __attribute__((ext_vector_type(8)));
typedef float    f32x4 __attribute__((ext_vector_type(4)));
typedef unsigned long long u64;
typedef unsigned short u16;

#define MFMA16(a, b, c) __builtin_amdgcn_mfma_f32_16x16x32_f16((a), (b), (c), 0, 0, 0)

__device__ __forceinline__ void gll16(const f16* g, f16* l) {
  __builtin_amdgcn_global_load_lds(
      (const __attribute__((address_space(1))) unsigned int*)g,
      (__attribute__((address_space(3))) unsigned int*)l, 16, 0, 0);
}

// swizzled fragment read from a [64 rows][64 f16] tile (128B rows, XOR-8 swz)
__device__ __forceinline__ f16x8 ldsfrag(const f16* tile, int row, int chunk) {
  return *(const f16x8*)&tile[row * 64 + ((chunk ^ (row & 7)) << 3)];
}

// --------------------------- convert fp32 -> hi/lo f16 ----------------------
__global__ __launch_bounds__(256) void cvt_split(const float4* __restrict__ s,
                                                 f16x4* __restrict__ hi,
                                                 f16x4* __restrict__ lo, int n4) {
  int i = blockIdx.x * 256 + threadIdx.x;
  if (i >= n4) return;
  float4 v = s[i];
  f16x4 h, l;
  h[0] = (f16)v.x; l[0] = (f16)(v.x - (float)h[0]);
  h[1] = (f16)v.y; l[1] = (f16)(v.y - (float)h[1]);
  h[2] = (f16)v.z; l[2] = (f16)(v.z - (float)h[2]);
  h[3] = (f16)v.w; l[3] = (f16)(v.w - (float)h[3]);
  hi[i] = h; lo[i] = l;
}

// --------------------------- mask -> bitmask --------------------------------
__global__ __launch_bounds__(256) void mask_bits(const float4* __restrict__ mask,
                                                 u16* __restrict__ bits16) {
  const size_t t = (size_t)blockIdx.x * 256 + threadIdx.x;  // 4,194,304 threads
  const float4 v0 = mask[t * 4 + 0];
  const float4 v1 = mask[t * 4 + 1];
  const float4 v2 = mask[t * 4 + 2];
  const float4 v3 = mask[t * 4 + 3];
  unsigned m = 0;
  m |= (v0.x > 1.f) ? 0x0001u : 0u;  m |= (v0.y > 1.f) ? 0x0002u : 0u;
  m |= (v0.z > 1.f) ? 0x0004u : 0u;  m |= (v0.w > 1.f) ? 0x0008u : 0u;
  m |= (v1.x > 1.f) ? 0x0010u : 0u;  m |= (v1.y > 1.f) ? 0x0020u : 0u;
  m |= (v1.z > 1.f) ? 0x0040u : 0u;  m |= (v1.w > 1.f) ? 0x0080u : 0u;
  m |= (v2.x > 1.f) ? 0x0100u : 0u;  m |= (v2.y > 1.f) ? 0x0200u : 0u;
  m |= (v2.z > 1.f) ? 0x0400u : 0u;  m |= (v2.w > 1.f) ? 0x0800u : 0u;
  m |= (v3.x > 1.f) ? 0x1000u : 0u;  m |= (v3.y > 1.f) ? 0x2000u : 0u;
  m |= (v3.z > 1.f) ? 0x4000u : 0u;  m |= (v3.w > 1.f) ? 0x8000u : 0u;
  bits16[t] = (u16)m;
}

// --------------------------- QKV projection GEMM ----------------------------
__global__ __launch_bounds__(256) void proj_gemm(
    const f16* __restrict__ qh, const f16* __restrict__ ql,
    const f16* __restrict__ wh, const f16* __restrict__ wl,
    const float* __restrict__ bias,
    f16* __restrict__ Qh, f16* __restrict__ Ql,
    f16* __restrict__ Kh, f16* __restrict__ Kl,
    f16* __restrict__ Vh) {
  __shared__ f16 Ah[128 * 32], Al[128 * 32], Bh[128 * 32], Bl[128 * 32];
  const int tid = threadIdx.x;
  const int bid = blockIdx.x;
  const int wg = (bid & 7) * 96 + (bid >> 3);  // XCD-chunked, 768%8==0
  const int m0 = (wg / 24) * 128, n0 = (wg % 24) * 128;
  const bool isv = (n0 >= 2048);
  const int wid = tid >> 6, lane = tid & 63;
  const int wm = (wid >> 1) * 64, wn = (wid & 1) * 64;
  const int r16 = lane & 15, g = lane >> 4;

  f32x4 zero4 = {0.f, 0.f, 0.f, 0.f};
  f32x4 acc[4][4];
#pragma unroll
  for (int i = 0; i < 4; ++i)
#pragma unroll
    for (int j = 0; j < 4; ++j) acc[i][j] = zero4;

  for (int s = 0; s < 32; ++s) {
    const int kk = s << 5;
    const f16* Abh = qh + (size_t)m0 * 1024 + kk;
    const f16* Abl = ql + (size_t)m0 * 1024 + kk;
    const f16* Bbh = wh + (size_t)n0 * 1024 + kk;
    const f16* Bbl = wl + (size_t)n0 * 1024 + kk;
#pragma unroll
    for (int it = 0; it < 2; ++it) {
      const int c = tid + it * 256;
      const int go = (c >> 2) * 1024 + (c & 3) * 8;
      gll16(Abh + go, &Ah[c * 8]);
      gll16(Bbh + go, &Bh[c * 8]);
      if (!isv) {
        gll16(Abl + go, &Al[c * 8]);
        gll16(Bbl + go, &Bl[c * 8]);
      }
    }
    __syncthreads();
    f16x8 a[4], al_[4];
#pragma unroll
    for (int i = 0; i < 4; ++i) {
      a[i] = *(const f16x8*)&Ah[(wm + i * 16 + r16) * 32 + g * 8];
      if (!isv) al_[i] = *(const f16x8*)&Al[(wm + i * 16 + r16) * 32 + g * 8];
    }
#pragma unroll
    for (int j = 0; j < 4; ++j) {
      const f16x8 b = *(const f16x8*)&Bh[(wn + j * 16 + r16) * 32 + g * 8];
      if (!isv) {
        const f16x8 bl = *(const f16x8*)&Bl[(wn + j * 16 + r16) * 32 + g * 8];
#pragma unroll
        for (int i = 0; i < 4; ++i) {
          acc[i][j] = MFMA16(a[i], b, acc[i][j]);
          acc[i][j] = MFMA16(al_[i], b, acc[i][j]);
          acc[i][j] = MFMA16(a[i], bl, acc[i][j]);
        }
      } else {
#pragma unroll
        for (int i = 0; i < 4; ++i) acc[i][j] = MFMA16(a[i], b, acc[i][j]);
      }
    }
    __syncthreads();
  }

#pragma unroll
  for (int j = 0; j < 4; ++j) {
    const int col = n0 + wn + j * 16 + r16;
    const float bv = bias[col];
#pragma unroll
    for (int i = 0; i < 4; ++i) {
#pragma unroll
      for (int rr = 0; rr < 4; ++rr) {
        const int m = m0 + wm + i * 16 + g * 4 + rr;
        const float c = acc[i][j][rr] + bv;
        const int bi = m >> 10, n = m & 1023;
        if (col < 1024) {
          const int z = bi * 16 + (col >> 6), dh = col & 63;
          const size_t idx = ((size_t)z * 1024 + n) * 64 + dh;
          f16 h = (f16)c;
          Qh[idx] = h; Ql[idx] = (f16)(c - (float)h);
        } else if (col < 2048) {
          const int c2 = col - 1024;
          const int z = bi * 16 + (c2 >> 6), dh = c2 & 63;
          const size_t idx = ((size_t)z * 1024 + n) * 64 + dh;
          f16 h = (f16)c;
          Kh[idx] = h; Kl[idx] = (f16)(c - (float)h);
        } else {
          const int c2 = col - 2048;
          const int z = bi * 16 + (c2 >> 6), dh = c2 & 63;
          Vh[((size_t)z * 1024 + n) * 64 + dh] = (f16)c;
        }
      }
    }
  }
}

// --------------------------- V transpose ------------------------------------
__global__ __launch_bounds__(256) void transp_v(const f16* __restrict__ Vh,
                                                f16* __restrict__ Vt) {
  __shared__ f16 t[64][80];
  const int z = blockIdx.y, nt = blockIdx.x;
  const int tid = threadIdx.x;
#pragma unroll
  for (int it = 0; it < 2; ++it) {
    int c = tid + it * 256;
    int row = c >> 3, cc = c & 7;
    *(f16x8*)&t[row][cc * 8] =
        *(const f16x8*)&Vh[(((size_t)z << 10) + nt * 64 + row) * 64 + cc * 8];
  }
  __syncthreads();
#pragma unroll
  for (int it = 0; it < 2; ++it) {
    int c = tid + it * 256;
    int dh = c >> 3, ncc = c & 7;
    f16x8 o;
#pragma unroll
    for (int j = 0; j < 8; ++j) o[j] = t[ncc * 8 + j][dh];
    *(f16x8*)&Vt[((size_t)z * 64 + dh) * 1024 + nt * 64 + ncc * 8] = o;
  }
}

// --------------------------- fused attention (swapped QK^T) -----------------
__global__ __launch_bounds__(512) void attn(
    const f16* __restrict__ Qh_, const f16* __restrict__ Ql_,
    const f16* __restrict__ Kh_, const f16* __restrict__ Kl_,
    const f16* __restrict__ Vt_, const u64* __restrict__ bits,
    float* __restrict__ out) {
  __shared__ f16 Khs[2][4096], Kls[2][4096], Vts[2][4096];  // 48 KB dbuf
  __shared__ f16 Ps[8][1024];                               // 16 KB P tiles

  const int bid = blockIdx.x;
  const int wg = (bid & 7) * 64 + (bid >> 3);  // XCD-chunked, 512%8==0
  const int qt = wg & 7, z = wg >> 3;
  const int q0 = qt * 128;
  const int tid = threadIdx.x, w = tid >> 6, lane = tid & 63;
  const int r16 = lane & 15, g = lane >> 4;

  const size_t zrow = (size_t)z << 10;
  const f16* qrh = Qh_ + (zrow + q0 + w * 16 + r16) * 64;
  const f16* qrl = Ql_ + (zrow + q0 + w * 16 + r16) * 64;
  f16x8 qa[2], qla[2];
#pragma unroll
  for (int ks = 0; ks < 2; ++ks) {
    qa[ks] = *(const f16x8*)&qrh[ks * 32 + g * 8];
    qla[ks] = *(const f16x8*)&qrl[ks * 32 + g * 8];
  }

  const f16* KzhB = Kh_ + zrow * 64;
  const f16* KzlB = Kl_ + zrow * 64;
  const f16* VzB = Vt_ + (size_t)z * 64 * 1024;
  const int sc = tid, srow = sc >> 3, ssc = ((sc & 7) ^ (srow & 7)) << 3;

#define STAGE(buf, k0_)                                                   \
  do {                                                                    \
    gll16(KzhB + (size_t)((k0_) + srow) * 64 + ssc, &Khs[buf][sc * 8]);   \
    gll16(KzlB + (size_t)((k0_) + srow) * 64 + ssc, &Kls[buf][sc * 8]);   \
    gll16(VzB + (size_t)srow * 1024 + (k0_) + ssc, &Vts[buf][sc * 8]);    \
  } while (0)

  STAGE(0, 0);

  float mrow = -1e30f, lrow = 0.f;  // state for qrow = r16 (per lane)
  f32x4 zero4 = {0.f, 0.f, 0.f, 0.f};
  f32x4 acc[4];  // C[qrow=g*4+rr][dh=df*16+r16]
#pragma unroll
  for (int df = 0; df < 4; ++df) acc[df] = zero4;

  const u64* browp = bits + (zrow + q0 + w * 16 + r16) * 16;
  f16* Pw = &Ps[w][0];
  f16* pwbase = Pw + r16 * 64 + (g & 1) * 4;
  const int pswz = r16 & 7, ghalf = g >> 1;
  __syncthreads();

  for (int kt = 0; kt < 16; ++kt) {
    const int cur = kt & 1;
    const int k0 = kt << 6;
    if (kt < 15) STAGE(cur ^ 1, k0 + 64);  // async prefetch of next tile

    const u64 bm = browp[kt];

    // ---- S^T = K Q^T (3-term hi/lo): lane -> keys cf*16+g*4+rr, qrow r16
    __builtin_amdgcn_s_setprio(1);
    f32x4 s[4];
#pragma unroll
    for (int cf = 0; cf < 4; ++cf) {
      const int krow = cf * 16 + r16;
      const f16x8 kh0 = ldsfrag(&Khs[cur][0], krow, g);
      const f16x8 kh1 = ldsfrag(&Khs[cur][0], krow, 4 + g);
      const f16x8 kl0 = ldsfrag(&Kls[cur][0], krow, g);
      const f16x8 kl1 = ldsfrag(&Kls[cur][0], krow, 4 + g);
      f32x4 t = zero4;
      t = MFMA16(kh0, qa[0], t);
      t = MFMA16(kh0, qla[0], t);
      t = MFMA16(kl0, qa[0], t);
      t = MFMA16(kh1, qa[1], t);
      t = MFMA16(kh1, qla[1], t);
      t = MFMA16(kl1, qa[1], t);
      s[cf] = t;
    }
    __builtin_amdgcn_s_setprio(0);

    float s8[4][4];
#pragma unroll
    for (int cf = 0; cf < 4; ++cf)
#pragma unroll
      for (int rr = 0; rr < 4; ++rr) s8[cf][rr] = s[cf][rr] * 8.0f;

    float m16 = s8[0][0];
#pragma unroll
    for (int cf = 0; cf < 4; ++cf)
#pragma unroll
      for (int rr = 0; rr < 4; ++rr) m16 = fmaxf(m16, s8[cf][rr]);
    m16 = fmaxf(m16, __shfl_xor(m16, 16, 64));
    m16 = fmaxf(m16, __shfl_xor(m16, 32, 64));

    if (!__all(m16 <= mrow + 8.f)) {  // defer-max (T13)
      const float mnew = fmaxf(mrow, m16);
      const float scal = __expf(mrow - mnew);
      mrow = mnew;
      lrow *= scal;
      float sq[4];
#pragma unroll
      for (int rr = 0; rr < 4; ++rr) sq[rr] = __shfl(scal, g * 4 + rr, 16);
#pragma unroll
      for (int df = 0; df < 4; ++df)
#pragma unroll
        for (int rr = 0; rr < 4; ++rr) acc[df][rr] *= sq[rr];
    }

    float p_[4][4], rs = 0.f;
#pragma unroll
    for (int cf = 0; cf < 4; ++cf)
#pragma unroll
      for (int rr = 0; rr < 4; ++rr) {
        p_[cf][rr] = __expf(s8[cf][rr] - mrow);
        rs += p_[cf][rr];
      }
    rs += __shfl_xor(rs, 16, 64);
    rs += __shfl_xor(rs, 32, 64);
    lrow += rs;

    // ---- dropout bit-select + P via 4x ds_write_b64 ----
#pragma unroll
    for (int cf = 0; cf < 4; ++cf) {
      f16x4 pk;
#pragma unroll
      for (int rr = 0; rr < 4; ++rr) {
        const int key = cf * 16 + g * 4 + rr;
        pk[rr] = ((bm >> key) & 1ull) ? (f16)(p_[cf][rr] + p_[cf][rr]) : (f16)0.f;
      }
      *(f16x4*)&pwbase[(((cf * 2 + ghalf) ^ pswz) << 3)] = pk;
    }
    f16x8 pf[2];
#pragma unroll
    for (int ks2 = 0; ks2 < 2; ++ks2)
      pf[ks2] = ldsfrag(Pw, r16, ks2 * 4 + g);

    // ---- PV from staged V^T tile ----
    __builtin_amdgcn_s_setprio(1);
#pragma unroll
    for (int df = 0; df < 4; ++df)
#pragma unroll
      for (int ks2 = 0; ks2 < 2; ++ks2)
        acc[df] = MFMA16(pf[ks2],
                         ldsfrag(&Vts[cur][0], df * 16 + r16, ks2 * 4 + g),
                         acc[df]);
    __builtin_amdgcn_s_setprio(0);
    __syncthreads();
  }

  // ---- epilogue: redistribute 1/l from r16-indexed to (g,rr)-indexed ----
  const float rl = 1.0f / lrow;
  float rlq[4];
#pragma unroll
  for (int rr = 0; rr < 4; ++rr) rlq[rr] = __shfl(rl, g * 4 + rr, 16);
  const int bi = z >> 4, hh = z & 15;
#pragma unroll
  for (int df = 0; df < 4; ++df)
#pragma unroll
    for (int rr = 0; rr < 4; ++rr) {
      const int n = q0 + w * 16 + g * 4 + rr;
      out[((size_t)bi * 1024 + n) * 1024 + hh * 64 + df * 16 + r16] =
          acc[df][rr] * rlq[rr];
    }
#undef STAGE
}

// --------------------------- launcher ---------------------------------------
extern "C" void kernel_launch(void* const* d_in, const int* in_sizes, int n_in,
                              void* d_out, int out_size, void* d_ws,
                              size_t ws_size, hipStream_t stream) {
  const float* query = (const float*)d_in[0];
  const float* W = (const float*)d_in[3];
  const float* bias = (const float*)d_in[4];
  const float* mask = (const float*)d_in[5];
  float* out = (float*)d_out;

  f16* p = (f16*)d_ws;
  f16* qh = p;              p += (size_t)4096 * 1024;
  f16* ql = p;              p += (size_t)4096 * 1024;
  f16* wh = p;              p += (size_t)3072 * 1024;
  f16* wl = p;              p += (size_t)3072 * 1024;
  f16* Qh = p;              p += (size_t)64 * 1024 * 64;
  f16* Ql = p;              p += (size_t)64 * 1024 * 64;
  f16* Kh = p;              p += (size_t)64 * 1024 * 64;
  f16* Kl = p;              p += (size_t)64 * 1024 * 64;
  f16* Vh = p;              p += (size_t)64 * 1024 * 64;
  f16* Vt = p;              p += (size_t)64 * 1024 * 64;
  u64* bits = (u64*)p;      // 64*1024*16 u64 = 8.4 MB

  mask_bits<<<16384, 256, 0, stream>>>((const float4*)mask, (u16*)bits);
  cvt_split<<<(1048576 + 255) / 256, 256, 0, stream>>>(
      (const float4*)query, (f16x4*)qh, (f16x4*)ql, 1048576);
  cvt_split<<<(786432 + 255) / 256, 256, 0, stream>>>(
      (const float4*)W, (f16x4*)wh, (f16x4*)wl, 786432);
  proj_gemm<<<768, 256, 0, stream>>>(qh, ql, wh, wl, bias, Qh, Ql, Kh, Kl, Vh);
  transp_v<<<dim3(16, 64), 256, 0, stream>>>(Vh, Vt);
  attn<<<512, 512, 0, stream>>>(Qh, Ql, Kh, Kl, Vt, bits, out);
}